// Round 7
// baseline (1028.707 us; speedup 1.0000x reference)
//
#include <hip/hip_runtime.h>
#include <stdint.h>
#include <stddef.h>

// ---------------- problem constants ----------------
#define BATCH 8
#define NPT   2048
#define NB    (BATCH*NPT)            // 16384
#define CAP   128                    // max sparse entries per row/col
#define ITERS 100
#define TPB   1024
#define NWAVE (TPB/64)
#define C50      1.9287498479639178e-22f   // expf(-50.f) == clamp floor of K
#define MUV      (1.0f/2048.0f)
#define EPS_DIVF 1e-8f

// ---------------- workspace layout (bytes), 16B-aligned ----------------
#define OFF_GMAX 0u                                   // gmax[dir][b*32+g]
#define OFF_CNT  4096u                                // cnt[dir][b][n], 128 KB
#define OFF_PERM (OFF_CNT + (size_t)2*NB*4)           // u16 perm[dir][b][p] (sorted pos -> orig)
#define OFF_IPM  (OFF_PERM + (size_t)2*NB*2)          // u16 ipm[dir][b][n] (orig -> sorted pos)
#define OFF_SPTS (OFF_IPM + (size_t)2*NB*2)           // float4 staged points
#define OFF_TPTS (OFF_SPTS + (size_t)NB*16)
#define OFF_U    (OFF_TPTS + (size_t)NB*16)
#define OFF_V    (OFF_U + (size_t)NB*4)
#define OFF_ROWE (OFF_V + (size_t)NB*4)               // ELL-T4 slab (sorted rows), 8 MB
#define OFF_COLE (OFF_ROWE + (size_t)NB*CAP*4)        // 8 MB
// total ~17.6 MB

// Pack: [31:13] = (K-C50) with 10-bit mantissa (round-to-nearest), [12:2] = sorted idx*4.
__device__ __forceinline__ uint32_t pack_entry(float kv, uint32_t sidx) {
    uint32_t bb = __float_as_uint(kv);
    bb = (bb + 0x1000u) & 0xFFFFE000u;
    return bb | (sidx << 2);
}

// ELL-T4 address of entry slot `ofs` of sorted-row `p` within a batch slab (dword units)
__device__ __forceinline__ size_t ellt4_addr(uint32_t ofs, int p) {
    return (size_t)(ofs >> 2) * (NPT*4) + (size_t)p * 4 + (ofs & 3);
}

// gather: bits [12:2] of a packed entry are already the byte offset idx*4
__device__ __forceinline__ float gath(const float* w, uint32_t e) {
    return *(const float*)((const char*)w + (e & 0x1FFCu));
}

// ========== kernel A: stage float4 points + per-row/col entry counts ==========
extern "C" __global__ __launch_bounds__(TPB, 2)
void emd_count_56831007261025(const float* __restrict__ src,
                              const float* __restrict__ tgt,
                              uint8_t* __restrict__ wsb,
                              float* __restrict__ out)
{
    __shared__ float4 opts[NPT];

    uint32_t* cnt   = (uint32_t*)(wsb + OFF_CNT);
    float4*   gspts = (float4*)  (wsb + OFF_SPTS);
    float4*   gtpts = (float4*)  (wsb + OFF_TPTS);

    const int tid  = threadIdx.x;
    const int lane = tid & 63;
    const int wid  = tid >> 6;
    const int b    = blockIdx.x >> 5;
    const int g    = blockIdx.x & 31;
    const size_t base = (size_t)b * NPT;

    if (blockIdx.x == 0 && tid == 0) *out = 0.0f;

    if (tid < 64) {
        size_t gi = base + g*64 + tid;
        gspts[gi] = make_float4(src[3*gi], src[3*gi+1], src[3*gi+2], 0.0f);
        gtpts[gi] = make_float4(tgt[3*gi], tgt[3*gi+1], tgt[3*gi+2], 0.0f);
    }

    for (int pass = 0; pass < 2; ++pass) {
        const float* mineRaw  = pass ? tgt : src;
        const float* cloudRaw = pass ? src : tgt;

        __syncthreads();
        for (int i = tid; i < NPT; i += TPB) {
            size_t gi = base + i;
            opts[i] = make_float4(cloudRaw[3*gi], cloudRaw[3*gi+1], cloudRaw[3*gi+2], 0.0f);
        }
        __syncthreads();

        for (int r = 0; r < 4; ++r) {
            int n = g*64 + wid*4 + r;
            size_t gi = base + n;
            float4 sp = make_float4(mineRaw[3*gi], mineRaw[3*gi+1], mineRaw[3*gi+2], 0.0f);
            uint32_t c = 0;
            for (int mb = 0; mb < NPT; mb += 64) {
                float4 tp = opts[mb + lane];
                float dx = sp.x - tp.x, dy = sp.y - tp.y, dz = sp.z - tp.z;
                float d2 = dx*dx + dy*dy + dz*dz;
                c += (uint32_t)__popcll(__ballot(d2 < 0.25f));
            }
            if (lane == 0) cnt[(size_t)pass*NB + gi] = (c < CAP) ? c : CAP;
        }
    }
}

// ========== kernel B: counting-sort rows by count; emit perm, inverse perm, group max ==========
extern "C" __global__ __launch_bounds__(256, 4)
void emd_sort_56831007261025(uint8_t* __restrict__ wsb)
{
    __shared__ uint32_t hist[CAP+2];
    __shared__ uint32_t bofs[CAP+2];
    __shared__ uint16_t permL[NPT];

    const int tid = threadIdx.x;
    const int dir = blockIdx.x >> 3;
    const int b   = blockIdx.x & 7;

    const uint32_t* cnt  = (const uint32_t*)(wsb + OFF_CNT) + (size_t)dir*NB + (size_t)b*NPT;
    uint16_t*       perm = (uint16_t*)(wsb + OFF_PERM) + (size_t)dir*NB + (size_t)b*NPT;
    uint16_t*       ipm  = (uint16_t*)(wsb + OFF_IPM)  + (size_t)dir*NB + (size_t)b*NPT;
    uint32_t*       gmax = (uint32_t*)(wsb + OFF_GMAX) + (size_t)dir*256 + (size_t)b*32;

    for (int i = tid; i < CAP+2; i += 256) hist[i] = 0;
    __syncthreads();
    for (int n = tid; n < NPT; n += 256) atomicAdd(&hist[cnt[n]], 1u);
    __syncthreads();
    if (tid == 0) {
        uint32_t run = 0;
        for (int i = 0; i < CAP+2; ++i) { bofs[i] = run; run += hist[i]; }
    }
    __syncthreads();
    for (int n = tid; n < NPT; n += 256) {
        uint32_t p = atomicAdd(&bofs[cnt[n]], 1u);
        permL[p] = (uint16_t)n;
    }
    __syncthreads();
    for (int p = tid; p < NPT; p += 256) {
        uint16_t n = permL[p];
        perm[p] = n;
        ipm[n]  = (uint16_t)p;
    }
    if (tid < 32) gmax[tid] = cnt[permL[tid*64 + 63]];   // ascending sort -> group max
}

// ========== kernel C: build ELL-T4 slabs, spread-placement bank schedule ==========
// Entry order within a row is free (sum commutes). Sort each row's entries by key
// (bank + pos) & 31, then place rank r at slot floor(r*L/cnt) where L = jm4*4 is the
// GROUP-uniform padded length. At read slot s, every lane's key ~= 32s/L (uniform
// across the wave) so bank ~= 32s/L - lane -> near-permutation across 32 banks.
// Padding slots hold entry 0 -> all lanes gather win[0] -> broadcast (free).
extern "C" __global__ __launch_bounds__(TPB, 2)
void emd_build_56831007261025(uint8_t* __restrict__ wsb)
{
    __shared__ float4   opts[NPT];        // 32 KB
    __shared__ uint16_t rows[64];
    __shared__ uint16_t ipmL[NPT];        // 4 KB
    __shared__ uint32_t scr[NWAVE][CAP];  // 8 KB per-wave entry scratch

    const float4* gspts = (const float4*)(wsb + OFF_SPTS);
    const float4* gtpts = (const float4*)(wsb + OFF_TPTS);
    uint32_t*     rowE  = (uint32_t*)(wsb + OFF_ROWE);
    uint32_t*     colE  = (uint32_t*)(wsb + OFF_COLE);
    const uint32_t* gmax = (const uint32_t*)(wsb + OFF_GMAX);

    const int tid  = threadIdx.x;
    const int lane = tid & 63;
    const int wid  = tid >> 6;
    const int b    = blockIdx.x >> 5;
    const int g    = blockIdx.x & 31;
    const size_t base  = (size_t)b * NPT;
    const size_t ebase = (size_t)b * NPT * CAP;

    // zero-fill only the stripes iterate will read (j4 < group jmax4)
    const int jmA = ((int)gmax[(size_t)b*32 + g] + 3) >> 2;
    const int jmB = ((int)gmax[256 + (size_t)b*32 + g] + 3) >> 2;
    for (int idx = tid; idx < jmA*256; idx += TPB) {
        int j4 = idx >> 8, t = idx & 255;
        rowE[ebase + (size_t)j4*(NPT*4) + (size_t)g*256 + t] = 0u;
    }
    for (int idx = tid; idx < jmB*256; idx += TPB) {
        int j4 = idx >> 8, t = idx & 255;
        colE[ebase + (size_t)j4*(NPT*4) + (size_t)g*256 + t] = 0u;
    }

    for (int pass = 0; pass < 2; ++pass) {
        const float4* mine  = pass ? gtpts : gspts;
        const float4* cloud = pass ? gspts : gtpts;
        uint32_t*     E     = pass ? colE : rowE;
        const uint32_t L    = (uint32_t)(pass ? jmB : jmA) * 4;   // group padded length
        const uint16_t* perm = (const uint16_t*)(wsb + OFF_PERM) + (size_t)pass*NB + base;
        // entries reference the OTHER side; bake that side's sorted position:
        const uint16_t* ipmO = (const uint16_t*)(wsb + OFF_IPM) + (size_t)(pass ? 0 : 1)*NB + base;

        __syncthreads();
        for (int i = tid; i < NPT; i += TPB) {
            opts[i] = cloud[base + i];
            ipmL[i] = ipmO[i];
        }
        if (tid < 64) rows[tid] = perm[g*64 + tid];
        __syncthreads();

        for (int r = 0; r < 4; ++r) {
            int psort = g*64 + wid*4 + r;              // sorted position (slab row)
            int n     = rows[wid*4 + r];               // original row
            float4 sp = mine[base + n];
            uint32_t cnt = 0;
            for (int mb = 0; mb < NPT; mb += 64) {
                int m = mb + lane;
                float4 tp = opts[m];
                float dx = sp.x - tp.x, dy = sp.y - tp.y, dz = sp.z - tp.z;
                float d2 = dx*dx + dy*dy + dz*dz;
                bool p = d2 < 0.25f;
                uint64_t mask = __ballot(p);
                uint32_t ofs = cnt + (uint32_t)__popcll(mask & ((1ull << lane) - 1ull));
                if (p && ofs < CAP) {
                    float d  = sqrtf(d2);
                    float kv = expf(-100.0f * d) - C50;
                    scr[wid][ofs] = pack_entry(kv, (uint32_t)ipmL[m]);
                }
                cnt += (uint32_t)__popcll(mask);
            }
            if (cnt > CAP) cnt = CAP;
            // DS ops within a wave execute in issue order: scr writes visible below.
            if (cnt && lane < 32) {
                const uint32_t ks = (uint32_t)(psort & 31);
                // histogram of keys (lane == key)
                uint32_t h = 0;
                for (uint32_t k = 0; k < cnt; ++k) {
                    uint32_t key = (((scr[wid][k] >> 2) & 31u) + ks) & 31u;
                    h += (key == (uint32_t)lane);
                }
                // exclusive prefix over the 32 active lanes
                uint32_t x = h;
                #pragma unroll
                for (int o = 1; o < 32; o <<= 1) {
                    uint32_t t = __shfl_up(x, o, 64);
                    if (lane >= o) x += t;
                }
                uint32_t rank = x - h;
                // placement: rank r -> slot floor(r*L/cnt)  (injective since L >= cnt)
                for (uint32_t k = 0; k < cnt; ++k) {
                    uint32_t e = scr[wid][k];
                    uint32_t key = (((e >> 2) & 31u) + ks) & 31u;
                    if (key == (uint32_t)lane) {
                        uint32_t slot = (rank * L) / cnt;
                        E[ebase + ellt4_addr(slot, psort)] = e;
                        ++rank;
                    }
                }
            }
        }
    }
}

// ========== kernel D: Sinkhorn iterations, ONE block per batch ==========
extern "C" __global__ __launch_bounds__(TPB, 1)
void emd_iterate_56831007261025(uint8_t* __restrict__ wsb)
{
    __shared__ float    lus[NPT];         // u in dir0-sorted order
    __shared__ float    lvs[NPT];         // v in dir1-sorted order
    __shared__ float    red[2][NWAVE];
    __shared__ uint32_t cflag[NWAVE];
    __shared__ uint32_t gmL[2][32];

    float* gu = (float*)(wsb + OFF_U);
    float* gv = (float*)(wsb + OFF_V);

    const int tid  = threadIdx.x;
    const int lane = tid & 63;
    const int wid  = tid >> 6;
    const int b    = blockIdx.x;
    const size_t ebase = (size_t)b * NPT * CAP;

    const uint32_t* rowE = (const uint32_t*)(wsb + OFF_ROWE) + ebase;
    const uint32_t* colE = (const uint32_t*)(wsb + OFF_COLE) + ebase;
    const uint32_t* gmax = (const uint32_t*)(wsb + OFF_GMAX);

    if (tid < 32) {
        gmL[0][tid] = gmax[(size_t)b*32 + tid];
        gmL[1][tid] = gmax[256 + (size_t)b*32 + tid];
    }
    for (int i = tid; i < NPT; i += TPB) lvs[i] = 1.0f;   // v0 = ones (order irrelevant)
    __syncthreads();

    const int grpA = wid;            // small group (ascending sort)
    const int grpB = 31 - wid;       // large group -> jmB4 >= jmA4
    const int posA = grpA*64 + lane;
    const int posB = grpB*64 + lane;

    for (int ph = 0; ph < 2*ITERS; ++ph) {
        const bool up = (ph & 1) == 0;                    // u-phase reads v, writes u
        const uint32_t* E    = up ? rowE : colE;
        const float*    win  = up ? lvs : lus;
        float*          wout = up ? lus : lvs;
        const uint32_t* gm   = gmL[up ? 0 : 1];

        float Sw;
        if (ph == 0) {
            Sw = (float)NPT;                              // sum(v0) = 2048 exactly
        } else {
            float ss = 0.0f;
            #pragma unroll
            for (int w = 0; w < NWAVE; ++w) ss += red[(ph - 1) & 1][w];
            Sw = ss;
        }

        const int jmA4 = ((int)__builtin_amdgcn_readfirstlane(gm[grpA]) + 3) >> 2;
        const int jmB4 = ((int)__builtin_amdgcn_readfirstlane(gm[grpB]) + 3) >> 2;
        const uint32_t* epA = E + (size_t)posA * 4;
        const uint32_t* epB = E + (size_t)posB * 4;

        // two independent load->gather->fma chains per lane (2x MLP)
        float a0 = 0.0f, a1 = 0.0f, a2 = 0.0f, a3 = 0.0f;
        float c0 = 0.0f, c1 = 0.0f, c2 = 0.0f, c3 = 0.0f;
        int j4 = 0;
        #pragma unroll 2
        for (; j4 < jmA4; ++j4) {
            uint4 eA = *(const uint4*)(epA + (size_t)j4 * (NPT*4));
            uint4 eB = *(const uint4*)(epB + (size_t)j4 * (NPT*4));
            a0 = fmaf(__uint_as_float(eA.x & 0xFFFFE000u), gath(win, eA.x), a0);
            a1 = fmaf(__uint_as_float(eA.y & 0xFFFFE000u), gath(win, eA.y), a1);
            a2 = fmaf(__uint_as_float(eA.z & 0xFFFFE000u), gath(win, eA.z), a2);
            a3 = fmaf(__uint_as_float(eA.w & 0xFFFFE000u), gath(win, eA.w), a3);
            c0 = fmaf(__uint_as_float(eB.x & 0xFFFFE000u), gath(win, eB.x), c0);
            c1 = fmaf(__uint_as_float(eB.y & 0xFFFFE000u), gath(win, eB.y), c1);
            c2 = fmaf(__uint_as_float(eB.z & 0xFFFFE000u), gath(win, eB.z), c2);
            c3 = fmaf(__uint_as_float(eB.w & 0xFFFFE000u), gath(win, eB.w), c3);
        }
        #pragma unroll 4
        for (; j4 < jmB4; ++j4) {
            uint4 eB = *(const uint4*)(epB + (size_t)j4 * (NPT*4));
            c0 = fmaf(__uint_as_float(eB.x & 0xFFFFE000u), gath(win, eB.x), c0);
            c1 = fmaf(__uint_as_float(eB.y & 0xFFFFE000u), gath(win, eB.y), c1);
            c2 = fmaf(__uint_as_float(eB.z & 0xFFFFE000u), gath(win, eB.z), c2);
            c3 = fmaf(__uint_as_float(eB.w & 0xFFFFE000u), gath(win, eB.w), c3);
        }
        float KvA  = fmaf(C50, Sw, (a0 + a1) + (a2 + a3));
        float KvB  = fmaf(C50, Sw, (c0 + c1) + (c2 + c3));
        float valA = MUV / fmaxf(KvA, EPS_DIVF);
        float valB = MUV / fmaxf(KvB, EPS_DIVF);

        uint32_t chg = 0;
        if (!up) {
            chg |= (fabsf(valA - wout[posA]) > 2e-5f * valA);
            chg |= (fabsf(valB - wout[posB]) > 2e-5f * valB);
        }
        wout[posA] = valA;
        wout[posB] = valB;

        float psum = valA + valB;
        #pragma unroll
        for (int o = 32; o > 0; o >>= 1) psum += __shfl_down(psum, o, 64);
        if (lane == 0) red[ph & 1][wid] = psum;
        if (!up) {
            uint64_t m = __ballot(chg != 0);
            if (lane == 0) cflag[wid] = (m != 0ull) ? 1u : 0u;
        }
        __syncthreads();                                  // one barrier per phase
        if (!up) {
            uint32_t any = 0;
            #pragma unroll
            for (int w = 0; w < NWAVE; ++w) any |= cflag[w];
            if (!any) break;   // converged: remaining iterations change nothing material
        }
    }

    // un-permute to original order for the epilogue
    const uint16_t* prmU = (const uint16_t*)(wsb + OFF_PERM) + (size_t)b*NPT;
    const uint16_t* prmV = (const uint16_t*)(wsb + OFF_PERM) + (size_t)NB + (size_t)b*NPT;
    for (int i = tid; i < NPT; i += TPB) {
        gu[(size_t)b*NPT + prmU[i]] = lus[i];
        gv[(size_t)b*NPT + prmV[i]] = lvs[i];
    }
}

// ========== kernel E: dense EMD epilogue: sum u*K*v*d ==========
extern "C" __global__ __launch_bounds__(TPB, 2)
void emd_epilogue_56831007261025(const uint8_t* __restrict__ wsb,
                                 float* __restrict__ out)
{
    __shared__ float4 tp[NPT];
    __shared__ float  lvv[NPT];
    __shared__ float  red[NWAVE];

    const float4* gspts = (const float4*)(wsb + OFF_SPTS);
    const float4* gtpts = (const float4*)(wsb + OFF_TPTS);
    const float*  gu    = (const float*) (wsb + OFF_U);
    const float*  gv    = (const float*) (wsb + OFF_V);

    const int tid  = threadIdx.x;
    const int lane = tid & 63;
    const int wid  = tid >> 6;
    const int b    = blockIdx.x >> 5;
    const int g    = blockIdx.x & 31;
    const size_t base = (size_t)b * NPT;

    for (int i = tid; i < NPT; i += TPB) {
        tp[i]  = gtpts[base + i];
        lvv[i] = gv[base + i];
    }
    __syncthreads();

    float wacc = 0.0f;
    for (int r = 0; r < 4; ++r) {
        size_t gi = base + g*64 + wid*4 + r;
        float4 sp   = gspts[gi];
        float  uval = gu[gi];
        float racc = 0.0f;
        for (int mb = 0; mb < NPT; mb += 64) {
            int m = mb + lane;
            float4 t = tp[m];
            float dx = sp.x - t.x, dy = sp.y - t.y, dz = sp.z - t.z;
            float d = sqrtf(dx*dx + dy*dy + dz*dz);
            float K = fmaxf(expf(-100.0f * d), C50);    // == exp(-min(100d,50))
            racc = fmaf(K * d, lvv[m], racc);
        }
        #pragma unroll
        for (int o = 32; o > 0; o >>= 1) racc += __shfl_down(racc, o, 64);
        if (lane == 0) wacc = fmaf(uval, racc, wacc);
    }
    if (lane == 0) red[wid] = wacc;
    __syncthreads();
    if (tid == 0) {
        float t = 0.0f;
        #pragma unroll
        for (int w = 0; w < NWAVE; ++w) t += red[w];
        atomicAdd(out, t * 0.125f);                     // mean over 8 batches
    }
}

extern "C" void kernel_launch(void* const* d_in, const int* in_sizes, int n_in,
                              void* d_out, int out_size, void* d_ws, size_t ws_size,
                              hipStream_t stream)
{
    const float* src = (const float*)d_in[0];
    const float* tgt = (const float*)d_in[1];
    float* out = (float*)d_out;
    uint8_t* ws = (uint8_t*)d_ws;

    emd_count_56831007261025   <<<dim3(256), dim3(TPB), 0, stream>>>(src, tgt, ws, out);
    emd_sort_56831007261025    <<<dim3(16),  dim3(256), 0, stream>>>(ws);
    emd_build_56831007261025   <<<dim3(256), dim3(TPB), 0, stream>>>(ws);
    emd_iterate_56831007261025 <<<dim3(8),   dim3(TPB), 0, stream>>>(ws);
    emd_epilogue_56831007261025<<<dim3(256), dim3(TPB), 0, stream>>>(ws, out);
}